// Round 17
// baseline (321.333 us; speedup 1.0000x reference)
//
#include <hip/hip_runtime.h>
#include <hip/hip_bf16.h>

typedef __bf16 bf16x8 __attribute__((ext_vector_type(8)));
typedef float f32x4 __attribute__((ext_vector_type(4)));
typedef float f32x16 __attribute__((ext_vector_type(16)));
typedef unsigned short ushort_t;

#define S_LEN 4096
#define D_DIM 512
#define NBATCH 4
#define NROW (NBATCH * S_LEN)
#define QKSTR 1024   // fused QK buffer row stride (Q cols 0-511, K cols 512-1023)

static __device__ __forceinline__ ushort_t f2bf(float f) {
    __hip_bfloat16 h = __float2bfloat16(f);
    return __builtin_bit_cast(ushort_t, h);
}
static __device__ __forceinline__ float bf2f(ushort_t u) {
    unsigned int x = ((unsigned int)u) << 16;
    return __builtin_bit_cast(float, x);
}

typedef unsigned int __attribute__((address_space(1))) as1_uint;
typedef unsigned int __attribute__((address_space(3))) as3_uint;

// async 16B/lane global->LDS (wave-uniform LDS base + lane*16; global src per-lane)
static __device__ __forceinline__ void gll16(const ushort_t* src, ushort_t* dst) {
    __builtin_amdgcn_global_load_lds((const as1_uint*)(const void*)src,
                                     (as3_uint*)(void*)dst, 16, 0, 0);
}

// ---------------- fp32 -> bf16 convert (with optional scale) ----------------
__global__ void cvt_bf16_kernel(const float* __restrict__ src, ushort_t* __restrict__ dst,
                                int n4, float scale) {
    int i = blockIdx.x * blockDim.x + threadIdx.x;
    if (i >= n4) return;
    float4 v = reinterpret_cast<const float4*>(src)[i];
    ushort4 o;
    o.x = f2bf(v.x * scale);
    o.y = f2bf(v.y * scale);
    o.z = f2bf(v.z * scale);
    o.w = f2bf(v.w * scale);
    reinterpret_cast<ushort4*>(dst)[i] = o;
}

// ---------------- bf16 GEMM (m97-style): C[M][N] = A[M][K] * Bt[N][K]^T ----------------
__global__ __launch_bounds__(256) void gemm_bt(const ushort_t* __restrict__ A,
                                               const ushort_t* __restrict__ Bt,
                                               ushort_t* __restrict__ C,
                                               int M, int N, int K) {
    __shared__ ushort_t As[128 * 32];   // 8 KB, linear (gll16 dest)
    __shared__ ushort_t Bs[128 * 32];
    int tid = threadIdx.x;
    int w = tid >> 6, lane = tid & 63, c = lane & 15, g = lane >> 4;
    int m0 = blockIdx.x * 128, n0 = blockIdx.y * 128;
    int wm = (w >> 1) * 64, wn = (w & 1) * 64;

    f32x4 acc[4][4];
#pragma unroll
    for (int mi = 0; mi < 4; mi++)
#pragma unroll
        for (int ni = 0; ni < 4; ni++) acc[mi][ni] = (f32x4){0.f, 0.f, 0.f, 0.f};

    for (int k0 = 0; k0 < K; k0 += 32) {
        __syncthreads();
#pragma unroll
        for (int rr = 0; rr < 2; rr++) {
            int cl = rr * 256 + tid;
            int row = cl >> 2, slot = cl & 3;
            int ch = slot ^ ((row >> 1) & 3);
            gll16(A + (size_t)(m0 + row) * K + k0 + ch * 8, &As[cl * 8]);
            gll16(Bt + (size_t)(n0 + row) * K + k0 + ch * 8, &Bs[cl * 8]);
        }
        __syncthreads();   // gll16s drained

        bf16x8 af[4], bfr[4];
#pragma unroll
        for (int i2 = 0; i2 < 4; i2++) {
            int row = wm + i2 * 16 + c;
            af[i2] = *(const bf16x8*)(&As[row * 32 + (g ^ ((row >> 1) & 3)) * 8]);
        }
#pragma unroll
        for (int i2 = 0; i2 < 4; i2++) {
            int row = wn + i2 * 16 + c;
            bfr[i2] = *(const bf16x8*)(&Bs[row * 32 + (g ^ ((row >> 1) & 3)) * 8]);
        }
#pragma unroll
        for (int mi = 0; mi < 4; mi++)
#pragma unroll
            for (int ni = 0; ni < 4; ni++)
                acc[mi][ni] = __builtin_amdgcn_mfma_f32_16x16x32_bf16(af[mi], bfr[ni],
                                                                      acc[mi][ni], 0, 0, 0);
    }

#pragma unroll
    for (int mi = 0; mi < 4; mi++)
#pragma unroll
        for (int ni = 0; ni < 4; ni++)
#pragma unroll
            for (int j = 0; j < 4; j++)
                C[(size_t)(m0 + wm + mi * 16 + g * 4 + j) * N + n0 + wn + ni * 16 + c] =
                    f2bf(acc[mi][ni][j]);
}

// ------- flash attention partials: 4-way kv split, V-direct-global PV, 2 WGs/CU -------
// 512 WGs of 512 threads (2 WGs/CU: LDS 72.2 KB). WG (b, p, h 0..3): q-blocks j=p then 63-p;
// kv tiles t = h, h+4, ... (KVB=32), Ks double-buffered via gll16 (chunk-XOR swizzle).
// QK (16x16 swapped, R11): wave (r 0..3, d 0..1) computes S^T[16 kv of half d][16 q of r];
// P=exp(s-m_loc) -> WG-wide Ps[64][PPAD]; deferred correction via mhalf.
// PV (32x32x16, R13): wave w owns D cols [w*64,(w+1)*64); A=P corr-scaled per A-row (shfl),
// B=V read DIRECT from global (disjoint slices, no redundancy); o-rescale per C-row via
// shfl of lane-indexed alpha; mprevS parity pair. bf16 partials, 4-way global merge.
#define KVB 32
#define PPAD 40

__global__ __launch_bounds__(512, 2) void attn_part_kernel(const ushort_t* __restrict__ QK,
                                                           const ushort_t* __restrict__ Vt,
                                                           ushort_t* __restrict__ parts,
                                                           float* __restrict__ ml) {
    __shared__ ushort_t Ks[2][KVB][512];   // 64 KB (chunk-swizzled: pos = ch ^ (row&7))
    __shared__ ushort_t Ps[64 * PPAD];     // 5 KB: P[64 q][32 kv], row pad 40
    __shared__ float mhalf[2 * 64];
    __shared__ float lhalf[2 * 64];
    __shared__ float mprevS[2][64];        // parity pair: running max before this tile

    const int gid = blockIdx.x;
    const int b = gid & 3;
    const int h = (gid >> 2) & 3;          // kv parity 0..3
    const int p = gid >> 4;                // 0..31
    const int tid = threadIdx.x;
    const int w = tid >> 6, lane = tid & 63, c = lane & 15, g = lane >> 4;
    const int r = w & 3, d = w >> 2;       // QK roles: q row-group, kv-half
    const int l31 = lane & 31, l5 = lane >> 5;

    const ushort_t* Q  = QK;               // cols 0-511 of fused buffer
    const ushort_t* Kp = QK + 512;         // cols 512-1023

    const int sbase = b * S_LEN;
    ushort_t* po = parts + (size_t)h * NROW * D_DIM;

    for (int phase = 0; phase < 2; ++phase) {
        const int jblk = phase ? (63 - p) : p;
        const int qbase = jblk * 64;
        const int tl = 2 * jblk + 1;       // last 32-kv tile index

        // Q fragments (1/sqrt(512) folded into W_q)
        bf16x8 qf[16];
        {
            const ushort_t* qrow = Q + (size_t)(sbase + qbase + r * 16 + c) * QKSTR;
#pragma unroll
            for (int kk = 0; kk < 16; kk++)
                qf[kk] = *(const bf16x8*)(qrow + kk * 32 + g * 8);
        }

        f32x16 o[4];   // (q2, db): rows q2*32+..., cols w*64+db*32+l31
#pragma unroll
        for (int t = 0; t < 4; t++)
#pragma unroll
            for (int e = 0; e < 16; e++) o[t][e] = 0.f;
        float m_r = -1e30f, l_r = 0.f;     // per-lane QK chain: q-row = r*16 + c

        if (tid < 64) mprevS[0][tid] = -1e30f;

        // ---- prologue: stage K[first tile] into buf 0 ----
        if (h <= tl) {
            const ushort_t* kg = Kp + (size_t)(sbase + h * KVB) * QKSTR;
#pragma unroll
            for (int ii = 0; ii < 4; ii++) {
                int row = w * 4 + ii;
                gll16(kg + (size_t)row * QKSTR + ((lane ^ (row & 7)) * 8), &Ks[0][row][0]);
            }
        }
        __syncthreads();

        int it = 0;
        for (int t = h; t <= tl; t += 4, ++it) {
            const int cur = it & 1;
            const int kv0 = t * KVB;

            // ---- issue K-stage of tile t+4 into the other buffer ----
            if (t + 4 <= tl) {
                const ushort_t* kg = Kp + (size_t)(sbase + (t + 4) * KVB) * QKSTR;
#pragma unroll
                for (int ii = 0; ii < 4; ii++) {
                    int row = w * 4 + ii;
                    gll16(kg + (size_t)row * QKSTR + ((lane ^ (row & 7)) * 8),
                          &Ks[cur ^ 1][row][0]);
                }
            }
            // ---- issue V global loads (disjoint D-64 per wave; used after barrier A) ----
            bf16x8 vr[4];
            {
                const ushort_t* vb = Vt + (size_t)(w * 64 + l31) * NROW + sbase + kv0 + l5 * 8;
#pragma unroll
                for (int db = 0; db < 2; db++)
#pragma unroll
                    for (int st = 0; st < 2; st++)
                        vr[db * 2 + st] =
                            *(const bf16x8*)(vb + (size_t)db * 32 * NROW + st * 16);
            }

            // ---- QK^T : S^T[16 kv of half d][16 q of r], dual accumulator chains ----
            f32x4 s4 = (f32x4){0.f, 0.f, 0.f, 0.f};
            f32x4 s4b = (f32x4){0.f, 0.f, 0.f, 0.f};
            __builtin_amdgcn_s_setprio(1);
#pragma unroll
            for (int kk = 0; kk < 16; kk += 2) {
                bf16x8 kf0 = *(const bf16x8*)(
                    &Ks[cur][d * 16 + c][((4 * kk + g) ^ (c & 7)) * 8]);
                s4 = __builtin_amdgcn_mfma_f32_16x16x32_bf16(kf0, qf[kk], s4, 0, 0, 0);
                bf16x8 kf1 = *(const bf16x8*)(
                    &Ks[cur][d * 16 + c][((4 * (kk + 1) + g) ^ (c & 7)) * 8]);
                s4b = __builtin_amdgcn_mfma_f32_16x16x32_bf16(kf1, qf[kk + 1], s4b, 0, 0, 0);
            }
            __builtin_amdgcn_s_setprio(0);
            s4 = s4 + s4b;
            // s4[jj] = S[kv0 + d*16 + g*4 + jj][q = r*16 + c]

            // ---- causal mask (last two 32-kv tiles form the diagonal 64-block) ----
            if (t >= 2 * jblk) {
                int qrow = qbase + r * 16 + c;
#pragma unroll
                for (int jj = 0; jj < 4; jj++) {
                    int kvcol = kv0 + d * 16 + g * 4 + jj;
                    if (kvcol > qrow) s4[jj] = -1e38f;
                }
            }

            // ---- local (half) softmax; P = exp(s - m_loc) ----
            float pm = fmaxf(fmaxf(s4[0], s4[1]), fmaxf(s4[2], s4[3]));
            pm = fmaxf(pm, __shfl_xor(pm, 16, 64));
            pm = fmaxf(pm, __shfl_xor(pm, 32, 64));
            float m_loc = fmaxf(m_r, pm);
            float pv[4], rs = 0.f;
#pragma unroll
            for (int jj = 0; jj < 4; jj++) {
                pv[jj] = __expf(s4[jj] - m_loc);
                rs += pv[jj];
            }
            rs += __shfl_xor(rs, 16, 64);
            rs += __shfl_xor(rs, 32, 64);
            {
                ushort4 u;
                u.x = f2bf(pv[0]);
                u.y = f2bf(pv[1]);
                u.z = f2bf(pv[2]);
                u.w = f2bf(pv[3]);
                *(ushort4*)(&Ps[(r * 16 + c) * PPAD + d * 16 + g * 4]) = u;
            }
            if (g == 0) mhalf[d * 64 + r * 16 + c] = m_loc;
            __syncthreads();   // A: P + mhalf visible; K-stage + V loads drained

            // ---- per-row (lane-indexed) correction state: row = lane ----
            float mh0_l = mhalf[lane];
            float mh1_l = mhalf[64 + lane];
            float mn_l  = fmaxf(mh0_l, mh1_l);
            float al_l  = __expf(mprevS[cur][lane] - mn_l);
            if (w == 0) mprevS[cur ^ 1][lane] = mn_l;

            // ---- QK-chain l bookkeeping (own row r*16+c) ----
            {
                float mh0 = mhalf[r * 16 + c], mh1 = mhalf[64 + r * 16 + c];
                float mn = fmaxf(mh0, mh1);
                float alpha = __expf(m_r - mn);
                float corr_own = __expf((d ? mh1 : mh0) - mn);
                l_r = l_r * alpha + rs * corr_own;
                m_r = mn;
            }

            // ---- PV prep: A-row scale factors (row = q2*32+l31, via shfl) ----
            float cg2[2][2];
#pragma unroll
            for (int q2 = 0; q2 < 2; q2++) {
                int qa = q2 * 32 + l31;
                float mna = __shfl(mn_l, qa, 64);
                cg2[q2][0] = __expf(__shfl(mh0_l, qa, 64) - mna);
                cg2[q2][1] = __expf(__shfl(mh1_l, qa, 64) - mna);
            }
            // ---- o rescale per C-ROW (q = q2*32 + (reg&3)+8*(reg>>2)+4*l5) ----
            if (__any((int)(al_l != 1.f))) {
#pragma unroll
                for (int q2 = 0; q2 < 2; q2++)
#pragma unroll
                    for (int reg = 0; reg < 16; reg++) {
                        int q = q2 * 32 + (reg & 3) + 8 * (reg >> 2) + 4 * l5;
                        float a = __shfl(al_l, q, 64);
                        o[q2 * 2 + 0][reg] *= a;
                        o[q2 * 2 + 1][reg] *= a;
                    }
            }

            // ---- PV: 32x32x16, A = corr-scaled P frags, B = global V regs ----
            __builtin_amdgcn_s_setprio(1);
#pragma unroll
            for (int q2 = 0; q2 < 2; q2++)
#pragma unroll
                for (int st = 0; st < 2; st++) {
                    bf16x8 pr = *(const bf16x8*)(
                        &Ps[(q2 * 32 + l31) * PPAD + st * 16 + l5 * 8]);
                    float cc = cg2[q2][st];
                    bf16x8 pa;
#pragma unroll
                    for (int e = 0; e < 8; e++)
                        pa[e] = (__bf16)((float)pr[e] * cc);
                    o[q2 * 2 + 0] = __builtin_amdgcn_mfma_f32_32x32x16_bf16(
                        pa, vr[st], o[q2 * 2 + 0], 0, 0, 0);
                    o[q2 * 2 + 1] = __builtin_amdgcn_mfma_f32_32x32x16_bf16(
                        pa, vr[2 + st], o[q2 * 2 + 1], 0, 0, 0);
                }
            __builtin_amdgcn_s_setprio(0);

            __syncthreads();   // B: P reads done; next tile may overwrite Ps / read new K
        }

        // ---- epilogue: bf16 raw partials + (m, l_tot) ----
#pragma unroll
        for (int q2 = 0; q2 < 2; q2++)
#pragma unroll
            for (int db = 0; db < 2; db++)
#pragma unroll
                for (int reg = 0; reg < 16; reg++) {
                    int q = q2 * 32 + (reg & 3) + 8 * (reg >> 2) + 4 * l5;
                    int Dc = w * 64 + db * 32 + l31;
                    po[(size_t)(sbase + qbase + q) * D_DIM + Dc] =
                        f2bf(o[q2 * 2 + db][reg]);
                }
        if (g == 0) lhalf[d * 64 + r * 16 + c] = l_r;
        __syncthreads();
        if (d == 0 && g == 0) {
            int row = sbase + qbase + r * 16 + c;
            float l_tot = l_r + lhalf[64 + r * 16 + c];
            ml[((size_t)h * NROW + row) * 2 + 0] = m_r;
            ml[((size_t)h * NROW + row) * 2 + 1] = l_tot;
        }
        __syncthreads();   // LDS safe for next phase
    }
}

// ---------------- merge the four kv-parity bf16 partials -> f32 out ----------------
__global__ __launch_bounds__(256) void attn_merge_kernel(float* __restrict__ out,
                                                         const ushort_t* __restrict__ parts,
                                                         const float* __restrict__ ml) {
    int i = blockIdx.x * blockDim.x + threadIdx.x;   // 4-elem group index
    int row = i >> 7;                                 // 128 groups per row
    float m[4], l[4];
    float mm = -1e30f;
#pragma unroll
    for (int h = 0; h < 4; h++) {
        m[h] = ml[((size_t)h * NROW + row) * 2 + 0];
        l[h] = ml[((size_t)h * NROW + row) * 2 + 1];
        mm = fmaxf(mm, m[h]);
    }
    float a[4], lsum = 0.f;
#pragma unroll
    for (int h = 0; h < 4; h++) {
        a[h] = __expf(m[h] - mm);
        lsum += l[h] * a[h];
    }
    float inv = 1.f / lsum;
    float4 r = {0.f, 0.f, 0.f, 0.f};
#pragma unroll
    for (int h = 0; h < 4; h++) {
        ushort4 u = reinterpret_cast<const ushort4*>(parts + (size_t)h * NROW * D_DIM)[i];
        r.x += bf2f(u.x) * a[h];
        r.y += bf2f(u.y) * a[h];
        r.z += bf2f(u.z) * a[h];
        r.w += bf2f(u.w) * a[h];
    }
    r.x *= inv; r.y *= inv; r.z *= inv; r.w *= inv;
    reinterpret_cast<float4*>(out)[i] = r;
}

// ---------------- host launch ----------------
extern "C" void kernel_launch(void* const* d_in, const int* in_sizes, int n_in,
                              void* d_out, int out_size, void* d_ws, size_t ws_size,
                              hipStream_t stream) {
    const float* X  = (const float*)d_in[0];
    const float* Wq = (const float*)d_in[1];
    const float* Wk = (const float*)d_in[2];
    const float* Wv = (const float*)d_in[3];
    float* out = (float*)d_out;

    const int M = NROW;             // 16384
    const int Kd = D_DIM;           // 512
    const size_t XBF_BYTES  = (size_t)M * Kd * 2;        // 16.8 MB
    const size_t W_BYTES    = (size_t)Kd * Kd * 2;       // 0.5 MB
    const size_t QK_BYTES   = (size_t)M * QKSTR * 2;     // 33.6 MB

    char* p = (char*)d_ws;
    ushort_t* Xbf   = (ushort_t*)p;            p += XBF_BYTES;
    ushort_t* Wqkb  = (ushort_t*)p;            p += 2 * W_BYTES;   // [1024][512]
    ushort_t* Wvb   = (ushort_t*)p;            p += W_BYTES;
    ushort_t* QKb   = (ushort_t*)p;            p += QK_BYTES;      // [16384][1024]
    ushort_t* Vtb   = (ushort_t*)p;            p += XBF_BYTES;     // [512][16384]
    ushort_t* parts = (ushort_t*)p;            p += 4 * XBF_BYTES; // 4x bf16 partials
    float*    mlb   = (float*)p;               p += (size_t)4 * M * 2 * 4;

    const float qscale = 0.044194173824159216f;  // 1/sqrt(512)

    {
        int n4 = (M * Kd) / 4;
        cvt_bf16_kernel<<<(n4 + 255) / 256, 256, 0, stream>>>(X, Xbf, n4, 1.0f);
        int w4 = (Kd * Kd) / 4;
        cvt_bf16_kernel<<<(w4 + 255) / 256, 256, 0, stream>>>(Wq, Wqkb, w4, qscale);
        cvt_bf16_kernel<<<(w4 + 255) / 256, 256, 0, stream>>>(Wk, Wqkb + Kd * Kd, w4, 1.0f);
        cvt_bf16_kernel<<<(w4 + 255) / 256, 256, 0, stream>>>(Wv, Wvb, w4, 1.0f);
    }
    // fused [Q|K] projection: C[16384][1024] = X * [Wq;Wk]^T
    gemm_bt<<<dim3(M / 128, QKSTR / 128), 256, 0, stream>>>(Xbf, Wqkb, QKb, M, QKSTR, Kd);
    // V^T = Wv * X^T : C[512][16384]
    gemm_bt<<<dim3(Kd / 128, M / 128), 256, 0, stream>>>(Wvb, Xbf, Vtb, Kd, M, Kd);

    attn_part_kernel<<<512, 512, 0, stream>>>(QKb, Vtb, parts, mlb);
    attn_merge_kernel<<<(M * Kd / 4) / 256, 256, 0, stream>>>(out, parts, mlb);
}

// Round 18
// 238.317 us; speedup vs baseline: 1.3483x; 1.3483x over previous
//
#include <hip/hip_runtime.h>
#include <hip/hip_bf16.h>

typedef __bf16 bf16x8 __attribute__((ext_vector_type(8)));
typedef float f32x4 __attribute__((ext_vector_type(4)));
typedef unsigned short ushort_t;

#define S_LEN 4096
#define D_DIM 512
#define NBATCH 4
#define NROW (NBATCH * S_LEN)
#define QKSTR 1024   // fused QK buffer row stride (Q cols 0-511, K cols 512-1023)

static __device__ __forceinline__ ushort_t f2bf(float f) {
    __hip_bfloat16 h = __float2bfloat16(f);
    return __builtin_bit_cast(ushort_t, h);
}
static __device__ __forceinline__ float bf2f(ushort_t u) {
    unsigned int x = ((unsigned int)u) << 16;
    return __builtin_bit_cast(float, x);
}

typedef unsigned int __attribute__((address_space(1))) as1_uint;
typedef unsigned int __attribute__((address_space(3))) as3_uint;

// async 16B/lane global->LDS (wave-uniform LDS base + lane*16; global src per-lane)
static __device__ __forceinline__ void gll16(const ushort_t* src, ushort_t* dst) {
    __builtin_amdgcn_global_load_lds((const as1_uint*)(const void*)src,
                                     (as3_uint*)(void*)dst, 16, 0, 0);
}

// ---------------- fp32 -> bf16 convert (with optional scale) ----------------
__global__ void cvt_bf16_kernel(const float* __restrict__ src, ushort_t* __restrict__ dst,
                                int n4, float scale) {
    int i = blockIdx.x * blockDim.x + threadIdx.x;
    if (i >= n4) return;
    float4 v = reinterpret_cast<const float4*>(src)[i];
    ushort4 o;
    o.x = f2bf(v.x * scale);
    o.y = f2bf(v.y * scale);
    o.z = f2bf(v.z * scale);
    o.w = f2bf(v.w * scale);
    reinterpret_cast<ushort4*>(dst)[i] = o;
}

// ---- fused weight convert: Wq (scaled), Wk, Wv -> contiguous bf16 [3][Kd*Kd] ----
__global__ void cvt_w_kernel(const float* __restrict__ Wq, const float* __restrict__ Wk,
                             const float* __restrict__ Wv, ushort_t* __restrict__ dst,
                             int w4, float qscale) {
    int i = blockIdx.x * blockDim.x + threadIdx.x;
    if (i >= 3 * w4) return;
    int sel = i / w4, off = i - sel * w4;
    const float* src = sel == 0 ? Wq : (sel == 1 ? Wk : Wv);
    float scale = sel == 0 ? qscale : 1.0f;
    float4 v = reinterpret_cast<const float4*>(src)[off];
    ushort4 o;
    o.x = f2bf(v.x * scale);
    o.y = f2bf(v.y * scale);
    o.z = f2bf(v.z * scale);
    o.w = f2bf(v.w * scale);
    reinterpret_cast<ushort4*>(dst)[i] = o;
}

// ---------------- bf16 GEMM (m97-style): C[M][N] = A[M][K] * Bt[N][K]^T ----------------
__global__ __launch_bounds__(256) void gemm_bt(const ushort_t* __restrict__ A,
                                               const ushort_t* __restrict__ Bt,
                                               ushort_t* __restrict__ C,
                                               int M, int N, int K) {
    __shared__ ushort_t As[128 * 32];   // 8 KB, linear (gll16 dest)
    __shared__ ushort_t Bs[128 * 32];
    int tid = threadIdx.x;
    int w = tid >> 6, lane = tid & 63, c = lane & 15, g = lane >> 4;
    int m0 = blockIdx.x * 128, n0 = blockIdx.y * 128;
    int wm = (w >> 1) * 64, wn = (w & 1) * 64;

    f32x4 acc[4][4];
#pragma unroll
    for (int mi = 0; mi < 4; mi++)
#pragma unroll
        for (int ni = 0; ni < 4; ni++) acc[mi][ni] = (f32x4){0.f, 0.f, 0.f, 0.f};

    for (int k0 = 0; k0 < K; k0 += 32) {
        __syncthreads();
#pragma unroll
        for (int rr = 0; rr < 2; rr++) {
            int cl = rr * 256 + tid;
            int row = cl >> 2, slot = cl & 3;
            int ch = slot ^ ((row >> 1) & 3);
            gll16(A + (size_t)(m0 + row) * K + k0 + ch * 8, &As[cl * 8]);
            gll16(Bt + (size_t)(n0 + row) * K + k0 + ch * 8, &Bs[cl * 8]);
        }
        __syncthreads();   // gll16s drained

        bf16x8 af[4], bfr[4];
#pragma unroll
        for (int i2 = 0; i2 < 4; i2++) {
            int row = wm + i2 * 16 + c;
            af[i2] = *(const bf16x8*)(&As[row * 32 + (g ^ ((row >> 1) & 3)) * 8]);
        }
#pragma unroll
        for (int i2 = 0; i2 < 4; i2++) {
            int row = wn + i2 * 16 + c;
            bfr[i2] = *(const bf16x8*)(&Bs[row * 32 + (g ^ ((row >> 1) & 3)) * 8]);
        }
#pragma unroll
        for (int mi = 0; mi < 4; mi++)
#pragma unroll
            for (int ni = 0; ni < 4; ni++)
                acc[mi][ni] = __builtin_amdgcn_mfma_f32_16x16x32_bf16(af[mi], bfr[ni],
                                                                      acc[mi][ni], 0, 0, 0);
    }

#pragma unroll
    for (int mi = 0; mi < 4; mi++)
#pragma unroll
        for (int ni = 0; ni < 4; ni++)
#pragma unroll
            for (int j = 0; j < 4; j++)
                C[(size_t)(m0 + wm + mi * 16 + g * 4 + j) * N + n0 + wn + ni * 16 + c] =
                    f2bf(acc[mi][ni][j]);
}

// ------------- flash attention partials: kv-half-split QK with deferred correction -------------
// (R16 verbatim — best measured: attn ~184 us, total 241.7 us. bf16 partials, s_setprio
// around MFMA clusters, dual QK accumulator chains.)
#define KVB 32
#define PPAD 40

__global__ __launch_bounds__(512, 2) void attn_part_kernel(const ushort_t* __restrict__ QK,
                                                           const ushort_t* __restrict__ Vt,
                                                           ushort_t* __restrict__ part0,
                                                           ushort_t* __restrict__ part1,
                                                           float* __restrict__ ml) {
    __shared__ ushort_t Ks[2][KVB][512];      // 64 KB (chunk-swizzled: pos = ch ^ (row&7))
    __shared__ ushort_t Vs[2][512][KVB];      // 64 KB (chunk-swizzled)
    __shared__ ushort_t Ps[4 * 16 * PPAD];    // 5 KB, per-r-group shared
    __shared__ float mhalf[2 * 64];
    __shared__ float lhalf[2 * 64];

    const int gid = blockIdx.x;
    const int b = gid & 3;
    const int h = (gid >> 2) & 1;
    const int p = gid >> 3;            // 0..31
    const int tid = threadIdx.x;
    const int w = tid >> 6, lane = tid & 63, c = lane & 15, g = lane >> 4;
    const int r = w & 3, d = w >> 2;   // q row-group, kv-half / D-half

    const ushort_t* Q  = QK;           // cols 0-511 of fused buffer
    const ushort_t* Kp = QK + 512;     // cols 512-1023

    const int sbase = b * S_LEN;
    ushort_t* pw = Ps + r * 16 * PPAD;
    ushort_t* po = h ? part1 : part0;
    const int hc = (c ^ (c >> 2)) & 3;            // V-read swizzle hash
    const int vrr = lane >> 2, vpc = lane & 3;    // V-stage row/chunk within 16-row group
    const int vhh = (vrr ^ (vrr >> 2)) & 3;       // V-stage swizzle hash

    for (int phase = 0; phase < 2; ++phase) {
        const int jblk = phase ? (63 - p) : p;
        const int qbase = jblk * 64;

        // Q fragments (1/sqrt(512) folded into W_q); d-pair waves load the same 16 rows.
        bf16x8 qf[16];
        {
            const ushort_t* qrow = Q + (size_t)(sbase + qbase + r * 16 + c) * QKSTR;
#pragma unroll
            for (int kk = 0; kk < 16; kk++)
                qf[kk] = *(const bf16x8*)(qrow + kk * 32 + g * 8);
        }

        f32x4 o[16];
#pragma unroll
        for (int t = 0; t < 16; t++) o[t] = (f32x4){0.f, 0.f, 0.f, 0.f};
        float m_r = -1e30f, l_r = 0.f;   // per-lane chain: q-row = r*16 + c (own kv-half l)

        // ---- prologue: stage K[0] + V[0] into buf 0 ----
        {
            const int kv0 = h * KVB;
            const ushort_t* kg = Kp + (size_t)(sbase + kv0) * QKSTR;
#pragma unroll
            for (int ii = 0; ii < 4; ii++) {
                int row = w * 4 + ii;
                gll16(kg + (size_t)row * QKSTR + ((lane ^ (row & 7)) * 8), &Ks[0][row][0]);
            }
#pragma unroll
            for (int ii = 0; ii < 4; ii++) {
                int grp = w * 4 + ii;
                gll16(Vt + (size_t)(grp * 16 + vrr) * NROW + sbase + kv0 + ((vpc ^ vhh) * 8),
                      &Vs[0][grp * 16][0]);
            }
        }
        __syncthreads();   // buf0 staged (barrier drains vmcnt)

        for (int s = 0; s <= jblk; ++s) {
            const int cur = s & 1;
            const int kv0 = (h + 2 * s) * KVB;

            // ---- issue K-stage of stream tile s+1 (drains at barrier A, overlaps QK) ----
            if (s < jblk) {
                const int kv0n = (h + 2 * (s + 1)) * KVB;
                const ushort_t* kg = Kp + (size_t)(sbase + kv0n) * QKSTR;
#pragma unroll
                for (int ii = 0; ii < 4; ii++) {
                    int row = w * 4 + ii;
                    gll16(kg + (size_t)row * QKSTR + ((lane ^ (row & 7)) * 8),
                          &Ks[cur ^ 1][row][0]);
                }
            }

            // ---- QK^T : S^T[16 kv of half d][16 q of r], dual accumulator chains ----
            f32x4 s4 = (f32x4){0.f, 0.f, 0.f, 0.f};
            f32x4 s4b = (f32x4){0.f, 0.f, 0.f, 0.f};
            __builtin_amdgcn_s_setprio(1);
#pragma unroll
            for (int kk = 0; kk < 16; kk += 2) {
                bf16x8 kf0 = *(const bf16x8*)(
                    &Ks[cur][d * 16 + c][((4 * kk + g) ^ (c & 7)) * 8]);
                s4 = __builtin_amdgcn_mfma_f32_16x16x32_bf16(kf0, qf[kk], s4, 0, 0, 0);
                bf16x8 kf1 = *(const bf16x8*)(
                    &Ks[cur][d * 16 + c][((4 * (kk + 1) + g) ^ (c & 7)) * 8]);
                s4b = __builtin_amdgcn_mfma_f32_16x16x32_bf16(kf1, qf[kk + 1], s4b, 0, 0, 0);
            }
            __builtin_amdgcn_s_setprio(0);
            s4 = s4 + s4b;
            // s4[jj] = S[kv0 + d*16 + g*4 + jj][q = r*16 + c]

            // ---- causal mask (last stream tile touches the diagonal) ----
            if (s == jblk) {
                int qrow = qbase + r * 16 + c;
#pragma unroll
                for (int jj = 0; jj < 4; jj++) {
                    int kvcol = kv0 + d * 16 + g * 4 + jj;
                    if (kvcol > qrow) s4[jj] = -1e38f;
                }
            }

            // ---- local (half) softmax with m_loc; P = exp(s - m_loc) ----
            float pm = fmaxf(fmaxf(s4[0], s4[1]), fmaxf(s4[2], s4[3]));
            pm = fmaxf(pm, __shfl_xor(pm, 16, 64));
            pm = fmaxf(pm, __shfl_xor(pm, 32, 64));
            float m_loc = fmaxf(m_r, pm);
            float pv[4], rs = 0.f;
#pragma unroll
            for (int jj = 0; jj < 4; jj++) {
                pv[jj] = __expf(s4[jj] - m_loc);
                rs += pv[jj];
            }
            rs += __shfl_xor(rs, 16, 64);
            rs += __shfl_xor(rs, 32, 64);
            {
                ushort4 u;
                u.x = f2bf(pv[0]);
                u.y = f2bf(pv[1]);
                u.z = f2bf(pv[2]);
                u.w = f2bf(pv[3]);
                *(ushort4*)(&pw[c * PPAD + d * 16 + g * 4]) = u;
            }
            if (g == 0) mhalf[d * 64 + r * 16 + c] = m_loc;
            __syncthreads();   // A: P + mhalf visible; K-stage landed

            // ---- issue V-stage of stream tile s+1 (drains at barrier B, overlaps PV) ----
            if (s < jblk) {
                const int kv0n = (h + 2 * (s + 1)) * KVB;
#pragma unroll
                for (int ii = 0; ii < 4; ii++) {
                    int grp = w * 4 + ii;
                    gll16(Vt + (size_t)(grp * 16 + vrr) * NROW + sbase + kv0n +
                              ((vpc ^ vhh) * 8),
                          &Vs[cur ^ 1][grp * 16][0]);
                }
            }

            // ---- combine halves: mn, alpha, per-half corrections ----
            float mh0 = mhalf[r * 16 + c], mh1 = mhalf[64 + r * 16 + c];
            float mn = fmaxf(mh0, mh1);           // both already >= m_r
            float alpha = __expf(m_r - mn);       // == 1.0f exactly when max unchanged
            float corr_own = __expf((d ? mh1 : mh0) - mn);
            l_r = l_r * alpha + rs * corr_own;
            m_r = mn;

            // ---- rescale O (wave-uniform skip when all alphas == 1) ----
            if (__any((int)(alpha != 1.f))) {
                float aq[4];
#pragma unroll
                for (int jj = 0; jj < 4; jj++)
                    aq[jj] = __shfl(alpha, (lane & 48) | (g * 4 + jj), 64);
#pragma unroll
                for (int dt = 0; dt < 16; dt++)
#pragma unroll
                    for (int jj = 0; jj < 4; jj++) o[dt][jj] *= aq[jj];
            }

            // ---- pa read + per-lane half-correction (pa slice: g<2 -> half0, g>=2 -> half1) ----
            float corr_pa = __expf(((g >> 1) ? mh1 : mh0) - mn);
            bf16x8 pr = *(const bf16x8*)(&pw[c * PPAD + g * 8]);
            bf16x8 pa;
#pragma unroll
            for (int i2 = 0; i2 < 8; i2++)
                pa[i2] = (__bf16)((float)pr[i2] * corr_pa);

            // ---- PV : O[16 rows][256 cols (D-half d)] += P[16x32] * V[32x256] ----
            __builtin_amdgcn_s_setprio(1);
#pragma unroll
            for (int dt = 0; dt < 16; dt++) {
                bf16x8 vf = *(const bf16x8*)(&Vs[cur][d * 256 + dt * 16 + c][(g ^ hc) * 8]);
                o[dt] = __builtin_amdgcn_mfma_f32_16x16x32_bf16(pa, vf, o[dt], 0, 0, 0);
            }
            __builtin_amdgcn_s_setprio(0);

            __syncthreads();   // B: V-stage landed; buf[cur] + P reads done
        }

        // ---- epilogue: exchange per-half l, write bf16 raw partial + (m, l_tot) ----
        if (g == 0) lhalf[d * 64 + r * 16 + c] = l_r;
        __syncthreads();
        float l_tot = l_r + lhalf[(1 ^ d) * 64 + r * 16 + c];
#pragma unroll
        for (int dt = 0; dt < 16; dt++)
#pragma unroll
            for (int jj = 0; jj < 4; jj++)
                po[(size_t)(sbase + qbase + r * 16 + g * 4 + jj) * D_DIM +
                   d * 256 + dt * 16 + c] = f2bf(o[dt][jj]);
        if (d == 0 && g == 0) {
            int row = sbase + qbase + r * 16 + c;
            ml[((size_t)h * NROW + row) * 2 + 0] = m_r;
            ml[((size_t)h * NROW + row) * 2 + 1] = l_tot;
        }
        __syncthreads();   // mhalf/lhalf/buffers safe for next phase
    }
}

// ---------------- merge the two h-split bf16 partials -> f32 out ----------------
__global__ __launch_bounds__(256) void attn_merge_kernel(float* __restrict__ out,
                                                         const ushort_t* __restrict__ part0,
                                                         const ushort_t* __restrict__ part1,
                                                         const float* __restrict__ ml) {
    int i = blockIdx.x * blockDim.x + threadIdx.x;   // 4-elem group index
    int row = i >> 7;                                 // 128 groups per row
    float m0 = ml[(size_t)row * 2 + 0], l0 = ml[(size_t)row * 2 + 1];
    float m1 = ml[((size_t)NROW + row) * 2 + 0], l1 = ml[((size_t)NROW + row) * 2 + 1];
    float mm = fmaxf(m0, m1);
    float a0 = __expf(m0 - mm), a1 = __expf(m1 - mm);
    float inv = 1.f / (l0 * a0 + l1 * a1);
    ushort4 u0 = reinterpret_cast<const ushort4*>(part0)[i];
    ushort4 u1 = reinterpret_cast<const ushort4*>(part1)[i];
    float4 r;
    r.x = (bf2f(u0.x) * a0 + bf2f(u1.x) * a1) * inv;
    r.y = (bf2f(u0.y) * a0 + bf2f(u1.y) * a1) * inv;
    r.z = (bf2f(u0.z) * a0 + bf2f(u1.z) * a1) * inv;
    r.w = (bf2f(u0.w) * a0 + bf2f(u1.w) * a1) * inv;
    reinterpret_cast<float4*>(out)[i] = r;
}

// ---------------- host launch ----------------
extern "C" void kernel_launch(void* const* d_in, const int* in_sizes, int n_in,
                              void* d_out, int out_size, void* d_ws, size_t ws_size,
                              hipStream_t stream) {
    const float* X  = (const float*)d_in[0];
    const float* Wq = (const float*)d_in[1];
    const float* Wk = (const float*)d_in[2];
    const float* Wv = (const float*)d_in[3];
    float* out = (float*)d_out;

    const int M = NROW;             // 16384
    const int Kd = D_DIM;           // 512
    const size_t XBF_BYTES  = (size_t)M * Kd * 2;        // 16.8 MB
    const size_t W_BYTES    = (size_t)Kd * Kd * 2;       // 0.5 MB
    const size_t QK_BYTES   = (size_t)M * QKSTR * 2;     // 33.6 MB

    char* p = (char*)d_ws;
    ushort_t* Xbf   = (ushort_t*)p;            p += XBF_BYTES;
    ushort_t* Wqkb  = (ushort_t*)p;            p += 2 * W_BYTES;   // [1024][512]: Wq|Wk
    ushort_t* Wvb   = (ushort_t*)p;            p += W_BYTES;       // contiguous after Wqkb
    ushort_t* QKb   = (ushort_t*)p;            p += QK_BYTES;      // [16384][1024]
    ushort_t* Vtb   = (ushort_t*)p;            p += XBF_BYTES;     // [512][16384]
    ushort_t* part0 = (ushort_t*)p;            p += XBF_BYTES;     // bf16 partial h=0
    ushort_t* part1 = (ushort_t*)p;            p += XBF_BYTES;     // bf16 partial h=1
    float*    mlb   = (float*)p;               p += (size_t)2 * M * 2 * 4;

    const float qscale = 0.044194173824159216f;  // 1/sqrt(512)

    {
        int n4 = (M * Kd) / 4;
        cvt_bf16_kernel<<<(n4 + 255) / 256, 256, 0, stream>>>(X, Xbf, n4, 1.0f);
        int w4 = (Kd * Kd) / 4;
        cvt_w_kernel<<<(3 * w4 + 255) / 256, 256, 0, stream>>>(Wq, Wk, Wv, Wqkb, w4, qscale);
    }
    // fused [Q|K] projection: C[16384][1024] = X * [Wq;Wk]^T
    gemm_bt<<<dim3(M / 128, QKSTR / 128), 256, 0, stream>>>(Xbf, Wqkb, QKb, M, QKSTR, Kd);
    // V^T = Wv * X^T : C[512][16384]
    gemm_bt<<<dim3(Kd / 128, M / 128), 256, 0, stream>>>(Wvb, Xbf, Vtb, Kd, M, Kd);

    attn_part_kernel<<<256, 512, 0, stream>>>(QKb, Vtb, part0, part1, mlb);
    attn_merge_kernel<<<(M * Kd / 4) / 256, 256, 0, stream>>>(out, part0, part1, mlb);
}